// Round 18
// baseline (106.955 us; speedup 1.0000x reference)
//
#include <hip/hip_runtime.h>

#define GATE_SCALE 1.7015f
#define SX 32.0f
#define SW 1024.0f
#define DESCALE 3.0517578125e-05f   // 1/(SX*SW) = 2^-15

typedef __attribute__((ext_vector_type(4))) int   v4i;
typedef __attribute__((ext_vector_type(16))) int  v16i;

__device__ __forceinline__ void gl2lds16(const void* g, void* l) {
    __builtin_amdgcn_global_load_lds((const __attribute__((address_space(1))) void*)g,
                                     (__attribute__((address_space(3))) void*)l, 16, 0, 0);
}

__device__ __forceinline__ int q8(float v, float s) {
    int q = __float2int_rn(v * s);
    return q < -127 ? -127 : (q > 127 ? 127 : q);
}

// ---------------------------------------------------------------------------
// ONE dispatch. Per-panel producer/consumer sync via device-scope flags:
//   blocks 0..31  quantize A-panel bid  (xq rows bid*64..+63)
//   blocks 32..47 quantize B-panel bid-32 (wq rows (bid-32)*64..+63)
//   all blocks acquire-spin on flags[mp], flags[32+np] before first STAGE.
// Deadlock-free: grid 512 == co-residency capacity (64KB LDS, 2 blk/CU) and
// producers never wait before producing. Flags live in ws: first call after
// 0xAA poison syncs properly; replays see 1 and rewrite identical bytes.
// GEMM+apply body = R17 champion (64x64, BK=128B, ring-4, vmcnt(8), raw
// barriers, setprio, XCD-rectangle swizzle; gate->LDS; fused Horner apply,
// A-block antisymmetrized inline from L2-hot Ar/Ai).
// ---------------------------------------------------------------------------
__launch_bounds__(256, 2)
__global__ void mega_kernel(const float* __restrict__ xr, const float* __restrict__ xi,
                            const float* __restrict__ W,
                            const float* __restrict__ Arg, const float* __restrict__ Aig,
                            const float* __restrict__ bias,
                            signed char* __restrict__ xq, signed char* __restrict__ wq,
                            int* __restrict__ flags,
                            float* __restrict__ outr, float* __restrict__ outi) {
    __shared__ __align__(16) signed char lA[4][64 * 128];   // 32 KB
    __shared__ __align__(16) signed char lB[4][64 * 128];   // 32 KB
    const int tid = threadIdx.x;
    const int lane = tid & 63;
    const int wid = tid >> 6;                 // 0..3
    const int bid = blockIdx.x;
    const int x = bid & 7, l = bid >> 3;
    const int m0 = ((x & 3) * 8 + (l & 7)) * 64;
    const int n0 = ((x >> 2) * 8 + (l >> 3)) * 64;
    const int mp = m0 >> 6, np = n0 >> 6;     // panel ids

    // ---- producer: quantize one 64-row panel ----
    if (bid < 48) {
        const bool isA = bid < 32;
        const int row0 = (isA ? bid : bid - 32) * 64;
        signed char* dst = isA ? xq : wq;
        const float s = isA ? SX : SW;
        // 64 rows x 512 float4-chunks = 32768 chunks; 128 per thread.
        for (int c = tid; c < 32768; c += 256) {
            const int row = row0 + (c >> 9);
            const int k = (c & 511) * 4;
            float4 f;
            if (isA) {
                const float* src = (k < 1024) ? (xr + row * 1024 + k)
                                              : (xi + row * 1024 + k - 1024);
                f = *(const float4*)src;
            } else {
                f = *(const float4*)(W + row * 2048 + k);
            }
            int a = q8(f.x, s), b = q8(f.y, s), c2 = q8(f.z, s), d = q8(f.w, s);
            unsigned int packed = (a & 0xFF) | ((b & 0xFF) << 8) | ((c2 & 0xFF) << 16)
                                | ((unsigned)(d & 0xFF) << 24);
            *(unsigned int*)(dst + row * 2048 + k) = packed;
        }
        __threadfence();                      // agent fence: L2 writeback
        __syncthreads();
        if (tid == 0)
            __hip_atomic_store(&flags[bid], 1, __ATOMIC_RELEASE,
                               __HIP_MEMORY_SCOPE_AGENT);
    }

    // ---- consumer gate: wait for my two panels ----
    if (tid == 0) {
        while (__hip_atomic_load(&flags[mp], __ATOMIC_ACQUIRE,
                                 __HIP_MEMORY_SCOPE_AGENT) != 1)
            __builtin_amdgcn_s_sleep(8);
        while (__hip_atomic_load(&flags[32 + np], __ATOMIC_ACQUIRE,
                                 __HIP_MEMORY_SCOPE_AGENT) != 1)
            __builtin_amdgcn_s_sleep(8);
    }
    __syncthreads();
    __threadfence();                          // acquire side: invalidate caches

    // ================= GEMM (R17 body) =================
    const int wr = wid >> 1, wc = wid & 1;
    const int lo = lane & 31, hi = lane >> 5, lo3 = lane & 7;
    const int arow = wr * 32 + lo, brow = wc * 32 + lo;
    const int ar7 = arow & 7, br7 = brow & 7;

    v16i acc = {};

    #define STAGE(buf, k0)                                                          \
        {                                                                           \
            _Pragma("unroll")                                                       \
            for (int q = 0; q < 2; ++q) {                                           \
                int c = q * 256 + tid;                                              \
                int row = c >> 3, ks = (c & 7) ^ (row & 7);                         \
                gl2lds16(&xq[(m0 + row) * 2048 + (k0) + ks * 16], &lA[buf][c * 16]);\
            }                                                                       \
            _Pragma("unroll")                                                       \
            for (int q = 0; q < 2; ++q) {                                           \
                int c = q * 256 + tid;                                              \
                int row = c >> 3, ks = (c & 7) ^ (row & 7);                         \
                gl2lds16(&wq[(n0 + row) * 2048 + (k0) + ks * 16], &lB[buf][c * 16]);\
            }                                                                       \
        }

    #define TILE(t, vmstr, do_stage)                                               \
        {                                                                           \
            asm volatile("s_waitcnt vmcnt(" vmstr ")" ::: "memory");                \
            __builtin_amdgcn_s_barrier();                                           \
            const int b = (t) & 3;                                                  \
            v4i af[4], bf[4];                                                       \
            _Pragma("unroll")                                                       \
            for (int kk = 0; kk < 4; ++kk) {                                        \
                const int ch = ((2 * kk + hi) ^ ar7) << 4;                          \
                const int chb = ((2 * kk + hi) ^ br7) << 4;                         \
                af[kk] = *(const v4i*)&lA[b][arow * 128 + ch];                      \
                bf[kk] = *(const v4i*)&lB[b][brow * 128 + chb];                     \
            }                                                                       \
            if (do_stage) STAGE((((t) + 3) & 3), ((t) + 3) * 128);                  \
            __builtin_amdgcn_s_setprio(1);                                          \
            _Pragma("unroll")                                                       \
            for (int kk = 0; kk < 4; ++kk)                                          \
                acc = __builtin_amdgcn_mfma_i32_32x32x32_i8(af[kk], bf[kk], acc, 0, 0, 0); \
            __builtin_amdgcn_s_setprio(0);                                          \
        }

    STAGE(0, 0);
    STAGE(1, 128);
    STAGE(2, 256);
    for (int t = 0; t < 13; ++t) TILE(t, "8", true);
    TILE(13, "8", false);
    TILE(14, "4", false);
    TILE(15, "0", false);
    #undef TILE
    #undef STAGE

    // ---- gate epilogue -> LDS ----
    float* lds_g = (float*)&lA[0][0];        // [64 m-local][8 gcol-local]
    {
        const int ncol = n0 + wc * 32 + lo;
        const float bv = bias[ncol];
        const int gl = wc * 4 + (lo >> 3);
        #pragma unroll
        for (int r = 0; r < 16; ++r) {
            const int mloc = wr * 32 + (r & 3) + 8 * (r >> 2) + 4 * hi;
            float z = ((float)acc[r] * DESCALE + bv) * GATE_SCALE;
            float gate = 1.0f / (1.0f + __expf(-z));
            gate += __shfl_xor(gate, 1);
            gate += __shfl_xor(gate, 2);
            gate += __shfl_xor(gate, 4);
            if (lo3 == 0)
                lds_g[mloc * 8 + gl] = gate * 0.125f;
        }
    }
    __syncthreads();

    // ---- apply tail: A-block antisymmetrized inline from Ar/Ai ----
    {
        const int h = tid & 1, j = (tid >> 1) & 7, mb = tid >> 4;
        const int n = (n0 >> 3) + j;

        float Ar_[4][8], Ai_[4][8];
        const float* Arp = Arg + n * 64;
        const float* Aip = Aig + n * 64;
        #pragma unroll
        for (int r = 0; r < 4; ++r) {
            const int o = h * 4 + r;
            #pragma unroll
            for (int jj = 0; jj < 4; ++jj) {
                const int i1 = h * 4 + jj;
                Ar_[r][jj] = 0.5f * (Arp[o * 8 + i1] - Arp[i1 * 8 + o]);
                Ai_[r][jj] = 0.5f * (Aip[o * 8 + i1] + Aip[i1 * 8 + o]);
                const int i2 = (1 - h) * 4 + jj;
                Ar_[r][4 + jj] = 0.5f * (Arp[o * 8 + i2] - Arp[i2 * 8 + o]);
                Ai_[r][4 + jj] = 0.5f * (Aip[o * 8 + i2] + Aip[i2 * 8 + o]);
            }
        }

        #define CMV()                                                                   \
            {                                                                           \
                float pwr[4], pwi[4];                                                   \
                _Pragma("unroll")                                                       \
                for (int k2 = 0; k2 < 4; ++k2) {                                        \
                    pwr[k2] = __shfl_xor(wr2[k2], 1);                                   \
                    pwi[k2] = __shfl_xor(wi2[k2], 1);                                   \
                }                                                                       \
                _Pragma("unroll")                                                       \
                for (int r = 0; r < 4; ++r) {                                           \
                    float sr = 0.f, si = 0.f;                                           \
                    _Pragma("unroll")                                                   \
                    for (int jj = 0; jj < 4; ++jj) {                                    \
                        sr += Ar_[r][jj] * wr2[jj]     - Ai_[r][jj] * wi2[jj];          \
                        si += Ar_[r][jj] * wi2[jj]     + Ai_[r][jj] * wr2[jj];          \
                        sr += Ar_[r][4 + jj] * pwr[jj] - Ai_[r][4 + jj] * pwi[jj];      \
                        si += Ar_[r][4 + jj] * pwi[jj] + Ai_[r][4 + jj] * pwr[jj];      \
                    }                                                                   \
                    tr[r] = sr; ti[r] = si;                                             \
                }                                                                       \
            }

        #pragma unroll
        for (int mi = 0; mi < 4; ++mi) {
            const int mloc = mb + mi * 16;
            const int m = m0 + mloc;
            const int d = n * 8 + h * 4;
            const float4 fvr = *(const float4*)&xr[m * 1024 + d];
            const float4 fvi = *(const float4*)&xi[m * 1024 + d];
            float vr[4] = {fvr.x, fvr.y, fvr.z, fvr.w};
            float vi[4] = {fvi.x, fvi.y, fvi.z, fvi.w};
            const float gv = lds_g[mloc * 8 + j];
            const float c1 = -2.f * gv, c2 = -c1 * gv, c3 = -c2 * gv, c4 = -c3 * gv;
            float wr2[4], wi2[4], tr[4], ti[4];

            #pragma unroll
            for (int r = 0; r < 4; ++r) { wr2[r] = c4 * vr[r]; wi2[r] = c4 * vi[r]; }
            CMV();
            #pragma unroll
            for (int r = 0; r < 4; ++r) { wr2[r] = c3 * vr[r] + tr[r]; wi2[r] = c3 * vi[r] + ti[r]; }
            CMV();
            #pragma unroll
            for (int r = 0; r < 4; ++r) { wr2[r] = c2 * vr[r] + tr[r]; wi2[r] = c2 * vi[r] + ti[r]; }
            CMV();
            #pragma unroll
            for (int r = 0; r < 4; ++r) { wr2[r] = c1 * vr[r] + tr[r]; wi2[r] = c1 * vi[r] + ti[r]; }
            CMV();

            float4 s0 = {vr[0] + tr[0], vr[1] + tr[1], vr[2] + tr[2], vr[3] + tr[3]};
            float4 s1 = {vi[0] + ti[0], vi[1] + ti[1], vi[2] + ti[2], vi[3] + ti[3]};
            *(float4*)&outr[m * 1024 + d] = s0;
            *(float4*)&outi[m * 1024 + d] = s1;
        }
        #undef CMV
    }
}

// ---------------------------------------------------------------------------
extern "C" void kernel_launch(void* const* d_in, const int* in_sizes, int n_in,
                              void* d_out, int out_size, void* d_ws, size_t ws_size,
                              hipStream_t stream) {
    const float* xr = (const float*)d_in[0];
    const float* xi = (const float*)d_in[1];
    const float* Ar = (const float*)d_in[2];
    const float* Ai = (const float*)d_in[3];
    const float* W  = (const float*)d_in[4];
    const float* bg = (const float*)d_in[5];
    float* out = (float*)d_out;

    char* ws = (char*)d_ws;
    signed char* xq = (signed char*)(ws);            // 4194304 B
    signed char* wq = (signed char*)(ws + 4194304);  // 2097152 B
    int* flags = (int*)(ws + 6291456);               // 48 * 4 B

    hipLaunchKernelGGL(mega_kernel, dim3(512), dim3(256), 0, stream,
                       xr, xi, W, Ar, Ai, bg, xq, wq, flags,
                       out, out + 2 * 1024 * 1024);
}

// Round 19
// 38.338 us; speedup vs baseline: 2.7898x; 2.7898x over previous
//
#include <hip/hip_runtime.h>

#define GATE_SCALE 1.7015f
#define SX 32.0f
#define SW 1024.0f
#define DESCALE 3.0517578125e-05f   // 1/(SX*SW) = 2^-15

typedef __attribute__((ext_vector_type(4))) int   v4i;
typedef __attribute__((ext_vector_type(16))) int  v16i;

__device__ __forceinline__ void gl2lds16(const void* g, void* l) {
    __builtin_amdgcn_global_load_lds((const __attribute__((address_space(1))) void*)g,
                                     (__attribute__((address_space(3))) void*)l, 16, 0, 0);
}

__device__ __forceinline__ int q8(float v, float s) {
    int q = __float2int_rn(v * s);
    return q < -127 ? -127 : (q > 127 ? 127 : q);
}

// ---------------------------------------------------------------------------
// Kernel 1: pure quantize of x_cat and W to int8 (no Ac build — the apply
// tail antisymmetrizes inline from the L2-hot 64-KB Ar/Ai).
// ---------------------------------------------------------------------------
__global__ void convert_kernel(const float* __restrict__ xr, const float* __restrict__ xi,
                               const float* __restrict__ W,
                               signed char* __restrict__ xq, signed char* __restrict__ wq) {
    const int XCV = 2048 * 2048 / 4;
    const int WV  = 1024 * 2048 / 4;
    const int STR = 1024 * 256;
    for (int v = blockIdx.x * 256 + threadIdx.x; v < XCV + WV; v += STR) {
        float4 f;
        signed char* dst;
        float s;
        if (v < XCV) {
            int idx = v * 4;
            int m = idx >> 11;
            int k = idx & 2047;
            const float* src = (k < 1024) ? (xr + m * 1024 + k)
                                          : (xi + m * 1024 + k - 1024);
            f = *(const float4*)src;
            dst = xq + idx;
            s = SX;
        } else {
            int idx = (v - XCV) * 4;
            f = *(const float4*)(W + idx);
            dst = wq + idx;
            s = SW;
        }
        int a = q8(f.x, s), b = q8(f.y, s), c = q8(f.z, s), d = q8(f.w, s);
        unsigned int packed = (a & 0xFF) | ((b & 0xFF) << 8) | ((c & 0xFF) << 16)
                            | ((unsigned)(d & 0xFF) << 24);
        *(unsigned int*)dst = packed;
    }
}

// ---------------------------------------------------------------------------
// Kernel 2: FUSED i8 GEMM + gate + apply  (R17 champion body).
// GEMM: 64x64 tile, BK=128B, 4 waves (2x2), ring-4 LDS, counted vmcnt(8),
// raw barriers, setprio, XCD-rectangle swizzle, rule-21 XOR swizzle.
// Epilogue: gate -> LDS (lA[0], unread since TILE(12)), barrier, then apply:
// each thread handles the h-half of 4 sites; partner lane = t^1 (same wave).
// A-block antisymmetrized inline from Ar/Ai (verified in R18).
// ---------------------------------------------------------------------------
__launch_bounds__(256, 2)
__global__ void gemm_apply_kernel(const signed char* __restrict__ A,   // xq [2048][2048]
                                  const signed char* __restrict__ Bw,  // wq [1024][2048]
                                  const float* __restrict__ bias,      // [1024]
                                  const float* __restrict__ xr, const float* __restrict__ xi,
                                  const float* __restrict__ Arg, const float* __restrict__ Aig,
                                  float* __restrict__ outr, float* __restrict__ outi) {
    __shared__ __align__(16) signed char lA[4][64 * 128];   // 32 KB
    __shared__ __align__(16) signed char lB[4][64 * 128];   // 32 KB
    const int tid = threadIdx.x;
    const int lane = tid & 63;
    const int wid = tid >> 6;                 // 0..3
    const int bid = blockIdx.x;
    const int x = bid & 7, l = bid >> 3;
    const int m0 = ((x & 3) * 8 + (l & 7)) * 64;
    const int n0 = ((x >> 2) * 8 + (l >> 3)) * 64;
    const int wr = wid >> 1, wc = wid & 1;
    const int lo = lane & 31, hi = lane >> 5, lo3 = lane & 7;
    const int arow = wr * 32 + lo, brow = wc * 32 + lo;
    const int ar7 = arow & 7, br7 = brow & 7;

    v16i acc = {};

    #define STAGE(buf, k0)                                                          \
        {                                                                           \
            _Pragma("unroll")                                                       \
            for (int q = 0; q < 2; ++q) {                                           \
                int c = q * 256 + tid;                                              \
                int row = c >> 3, ks = (c & 7) ^ (row & 7);                         \
                gl2lds16(&A[(m0 + row) * 2048 + (k0) + ks * 16], &lA[buf][c * 16]); \
            }                                                                       \
            _Pragma("unroll")                                                       \
            for (int q = 0; q < 2; ++q) {                                           \
                int c = q * 256 + tid;                                              \
                int row = c >> 3, ks = (c & 7) ^ (row & 7);                         \
                gl2lds16(&Bw[(n0 + row) * 2048 + (k0) + ks * 16], &lB[buf][c * 16]);\
            }                                                                       \
        }

    #define TILE(t, vmstr, do_stage)                                               \
        {                                                                           \
            asm volatile("s_waitcnt vmcnt(" vmstr ")" ::: "memory");                \
            __builtin_amdgcn_s_barrier();                                           \
            const int b = (t) & 3;                                                  \
            v4i af[4], bf[4];                                                       \
            _Pragma("unroll")                                                       \
            for (int kk = 0; kk < 4; ++kk) {                                        \
                const int ch = ((2 * kk + hi) ^ ar7) << 4;                          \
                const int chb = ((2 * kk + hi) ^ br7) << 4;                         \
                af[kk] = *(const v4i*)&lA[b][arow * 128 + ch];                      \
                bf[kk] = *(const v4i*)&lB[b][brow * 128 + chb];                     \
            }                                                                       \
            if (do_stage) STAGE((((t) + 3) & 3), ((t) + 3) * 128);                  \
            __builtin_amdgcn_s_setprio(1);                                          \
            _Pragma("unroll")                                                       \
            for (int kk = 0; kk < 4; ++kk)                                          \
                acc = __builtin_amdgcn_mfma_i32_32x32x32_i8(af[kk], bf[kk], acc, 0, 0, 0); \
            __builtin_amdgcn_s_setprio(0);                                          \
        }

    STAGE(0, 0);
    STAGE(1, 128);
    STAGE(2, 256);
    for (int t = 0; t < 13; ++t) TILE(t, "8", true);
    TILE(13, "8", false);
    TILE(14, "4", false);
    TILE(15, "0", false);
    #undef TILE
    #undef STAGE

    // ---- gate epilogue -> LDS (reuse lA[0]) ----
    float* lds_g = (float*)&lA[0][0];        // [64 m-local][8 gcol-local]
    {
        const int ncol = n0 + wc * 32 + lo;
        const float bv = bias[ncol];
        const int gl = wc * 4 + (lo >> 3);
        #pragma unroll
        for (int r = 0; r < 16; ++r) {
            const int mloc = wr * 32 + (r & 3) + 8 * (r >> 2) + 4 * hi;
            float z = ((float)acc[r] * DESCALE + bv) * GATE_SCALE;
            float gate = 1.0f / (1.0f + __expf(-z));
            gate += __shfl_xor(gate, 1);
            gate += __shfl_xor(gate, 2);
            gate += __shfl_xor(gate, 4);
            if (lo3 == 0)
                lds_g[mloc * 8 + gl] = gate * 0.125f;
        }
    }
    __syncthreads();

    // ---- apply tail: A-block antisymmetrized inline from Ar/Ai ----
    {
        const int h = tid & 1, j = (tid >> 1) & 7, mb = tid >> 4;
        const int n = (n0 >> 3) + j;

        float Ar_[4][8], Ai_[4][8];
        const float* Arp = Arg + n * 64;
        const float* Aip = Aig + n * 64;
        #pragma unroll
        for (int r = 0; r < 4; ++r) {
            const int o = h * 4 + r;
            #pragma unroll
            for (int jj = 0; jj < 4; ++jj) {
                const int i1 = h * 4 + jj;
                Ar_[r][jj] = 0.5f * (Arp[o * 8 + i1] - Arp[i1 * 8 + o]);
                Ai_[r][jj] = 0.5f * (Aip[o * 8 + i1] + Aip[i1 * 8 + o]);
                const int i2 = (1 - h) * 4 + jj;
                Ar_[r][4 + jj] = 0.5f * (Arp[o * 8 + i2] - Arp[i2 * 8 + o]);
                Ai_[r][4 + jj] = 0.5f * (Aip[o * 8 + i2] + Aip[i2 * 8 + o]);
            }
        }

        #define CMV()                                                                   \
            {                                                                           \
                float pwr[4], pwi[4];                                                   \
                _Pragma("unroll")                                                       \
                for (int k2 = 0; k2 < 4; ++k2) {                                        \
                    pwr[k2] = __shfl_xor(wr2[k2], 1);                                   \
                    pwi[k2] = __shfl_xor(wi2[k2], 1);                                   \
                }                                                                       \
                _Pragma("unroll")                                                       \
                for (int r = 0; r < 4; ++r) {                                           \
                    float sr = 0.f, si = 0.f;                                           \
                    _Pragma("unroll")                                                   \
                    for (int jj = 0; jj < 4; ++jj) {                                    \
                        sr += Ar_[r][jj] * wr2[jj]     - Ai_[r][jj] * wi2[jj];          \
                        si += Ar_[r][jj] * wi2[jj]     + Ai_[r][jj] * wr2[jj];          \
                        sr += Ar_[r][4 + jj] * pwr[jj] - Ai_[r][4 + jj] * pwi[jj];      \
                        si += Ar_[r][4 + jj] * pwi[jj] + Ai_[r][4 + jj] * pwr[jj];      \
                    }                                                                   \
                    tr[r] = sr; ti[r] = si;                                             \
                }                                                                       \
            }

        #pragma unroll
        for (int mi = 0; mi < 4; ++mi) {
            const int mloc = mb + mi * 16;
            const int m = m0 + mloc;
            const int d = n * 8 + h * 4;
            const float4 fvr = *(const float4*)&xr[m * 1024 + d];
            const float4 fvi = *(const float4*)&xi[m * 1024 + d];
            float vr[4] = {fvr.x, fvr.y, fvr.z, fvr.w};
            float vi[4] = {fvi.x, fvi.y, fvi.z, fvi.w};
            const float gv = lds_g[mloc * 8 + j];
            const float c1 = -2.f * gv, c2 = -c1 * gv, c3 = -c2 * gv, c4 = -c3 * gv;
            float wr2[4], wi2[4], tr[4], ti[4];

            #pragma unroll
            for (int r = 0; r < 4; ++r) { wr2[r] = c4 * vr[r]; wi2[r] = c4 * vi[r]; }
            CMV();
            #pragma unroll
            for (int r = 0; r < 4; ++r) { wr2[r] = c3 * vr[r] + tr[r]; wi2[r] = c3 * vi[r] + ti[r]; }
            CMV();
            #pragma unroll
            for (int r = 0; r < 4; ++r) { wr2[r] = c2 * vr[r] + tr[r]; wi2[r] = c2 * vi[r] + ti[r]; }
            CMV();
            #pragma unroll
            for (int r = 0; r < 4; ++r) { wr2[r] = c1 * vr[r] + tr[r]; wi2[r] = c1 * vi[r] + ti[r]; }
            CMV();

            float4 s0 = {vr[0] + tr[0], vr[1] + tr[1], vr[2] + tr[2], vr[3] + tr[3]};
            float4 s1 = {vi[0] + ti[0], vi[1] + ti[1], vi[2] + ti[2], vi[3] + ti[3]};
            *(float4*)&outr[m * 1024 + d] = s0;
            *(float4*)&outi[m * 1024 + d] = s1;
        }
        #undef CMV
    }
}

// ---------------------------------------------------------------------------
extern "C" void kernel_launch(void* const* d_in, const int* in_sizes, int n_in,
                              void* d_out, int out_size, void* d_ws, size_t ws_size,
                              hipStream_t stream) {
    const float* xr = (const float*)d_in[0];
    const float* xi = (const float*)d_in[1];
    const float* Ar = (const float*)d_in[2];
    const float* Ai = (const float*)d_in[3];
    const float* W  = (const float*)d_in[4];
    const float* bg = (const float*)d_in[5];
    float* out = (float*)d_out;

    char* ws = (char*)d_ws;
    signed char* xq = (signed char*)(ws);            // 4194304 B
    signed char* wq = (signed char*)(ws + 4194304);  // 2097152 B

    hipLaunchKernelGGL(convert_kernel, dim3(1024), dim3(256), 0, stream,
                       xr, xi, W, xq, wq);
    hipLaunchKernelGGL(gemm_apply_kernel, dim3(512), dim3(256), 0, stream,
                       xq, wq, bg, xr, xi, Ar, Ai, out, out + 2 * 1024 * 1024);
}

// Round 20
// 35.711 us; speedup vs baseline: 2.9950x; 1.0736x over previous
//
#include <hip/hip_runtime.h>

#define GATE_SCALE 1.7015f
#define SX 32.0f
#define SW 1024.0f
#define DESCALE 3.0517578125e-05f   // 1/(SX*SW) = 2^-15

typedef __attribute__((ext_vector_type(4))) int   v4i;
typedef __attribute__((ext_vector_type(16))) int  v16i;

__device__ __forceinline__ void gl2lds16(const void* g, void* l) {
    __builtin_amdgcn_global_load_lds((const __attribute__((address_space(1))) void*)g,
                                     (__attribute__((address_space(3))) void*)l, 16, 0, 0);
}

__device__ __forceinline__ int q8(float v, float s) {
    int q = __float2int_rn(v * s);
    return q < -127 ? -127 : (q > 127 ? 127 : q);
}

// ---------------------------------------------------------------------------
// Kernel 1: quantize x_cat and W to int8 + build antisymmetrized complex A
// table Ac[n][o*8+i][2] (L2-resident, read with float4 loads in the tail).
// ---------------------------------------------------------------------------
__global__ void convert_kernel(const float* __restrict__ xr, const float* __restrict__ xi,
                               const float* __restrict__ W,
                               const float* __restrict__ Ar, const float* __restrict__ Ai,
                               signed char* __restrict__ xq, signed char* __restrict__ wq,
                               float* __restrict__ Ac) {
    int bx = blockIdx.x;
    if (bx >= 1024) {
        int v = (bx - 1024) * 256 + threadIdx.x;   // 0..8191
        if (v < 8192) {
            int n = v >> 6, t = v & 63, o = t >> 3, i = t & 7;
            const float* arn = Ar + n * 64;
            const float* ain = Ai + n * 64;
            float a_r = 0.5f * (arn[o * 8 + i] - arn[i * 8 + o]);
            float a_i = 0.5f * (ain[o * 8 + i] + ain[i * 8 + o]);
            Ac[n * 128 + t * 2]     = a_r;
            Ac[n * 128 + t * 2 + 1] = a_i;
        }
        return;
    }
    const int XCV = 2048 * 2048 / 4;
    const int WV  = 1024 * 2048 / 4;
    const int STR = 1024 * 256;
    for (int v = bx * 256 + threadIdx.x; v < XCV + WV; v += STR) {
        float4 f;
        signed char* dst;
        float s;
        if (v < XCV) {
            int idx = v * 4;
            int m = idx >> 11;
            int k = idx & 2047;
            const float* src = (k < 1024) ? (xr + m * 1024 + k)
                                          : (xi + m * 1024 + k - 1024);
            f = *(const float4*)src;
            dst = xq + idx;
            s = SX;
        } else {
            int idx = (v - XCV) * 4;
            f = *(const float4*)(W + idx);
            dst = wq + idx;
            s = SW;
        }
        int a = q8(f.x, s), b = q8(f.y, s), c = q8(f.z, s), d = q8(f.w, s);
        unsigned int packed = (a & 0xFF) | ((b & 0xFF) << 8) | ((c & 0xFF) << 16)
                            | ((unsigned)(d & 0xFF) << 24);
        *(unsigned int*)dst = packed;
    }
}

// ---------------------------------------------------------------------------
// Kernel 2: FUSED i8 GEMM + gate + apply  (R17 champion body, verbatim).
// GEMM: 64x64 tile, BK=128B, 4 waves (2x2), ring-4 LDS, counted vmcnt(8),
// raw barriers, setprio, XCD-rectangle swizzle, rule-21 XOR swizzle.
// Epilogue: gate -> LDS (lA[0], unread since TILE(12)), barrier, then apply:
// each thread handles the h-half of 4 sites; partner lane = t^1 (same wave);
// A-block read from the pre-antisymmetrized Ac table with float4 loads.
// ---------------------------------------------------------------------------
__launch_bounds__(256, 2)
__global__ void gemm_apply_kernel(const signed char* __restrict__ A,   // xq [2048][2048]
                                  const signed char* __restrict__ Bw,  // wq [1024][2048]
                                  const float* __restrict__ bias,      // [1024]
                                  const float* __restrict__ xr, const float* __restrict__ xi,
                                  const float* __restrict__ Ac,        // [128][64][2]
                                  float* __restrict__ outr, float* __restrict__ outi) {
    __shared__ __align__(16) signed char lA[4][64 * 128];   // 32 KB
    __shared__ __align__(16) signed char lB[4][64 * 128];   // 32 KB
    const int tid = threadIdx.x;
    const int lane = tid & 63;
    const int wid = tid >> 6;                 // 0..3
    const int bid = blockIdx.x;
    const int x = bid & 7, l = bid >> 3;
    const int m0 = ((x & 3) * 8 + (l & 7)) * 64;
    const int n0 = ((x >> 2) * 8 + (l >> 3)) * 64;
    const int wr = wid >> 1, wc = wid & 1;
    const int lo = lane & 31, hi = lane >> 5, lo3 = lane & 7;
    const int arow = wr * 32 + lo, brow = wc * 32 + lo;
    const int ar7 = arow & 7, br7 = brow & 7;

    v16i acc = {};

    #define STAGE(buf, k0)                                                          \
        {                                                                           \
            _Pragma("unroll")                                                       \
            for (int q = 0; q < 2; ++q) {                                           \
                int c = q * 256 + tid;                                              \
                int row = c >> 3, ks = (c & 7) ^ (row & 7);                         \
                gl2lds16(&A[(m0 + row) * 2048 + (k0) + ks * 16], &lA[buf][c * 16]); \
            }                                                                       \
            _Pragma("unroll")                                                       \
            for (int q = 0; q < 2; ++q) {                                           \
                int c = q * 256 + tid;                                              \
                int row = c >> 3, ks = (c & 7) ^ (row & 7);                         \
                gl2lds16(&Bw[(n0 + row) * 2048 + (k0) + ks * 16], &lB[buf][c * 16]);\
            }                                                                       \
        }

    #define TILE(t, vmstr, do_stage)                                               \
        {                                                                           \
            asm volatile("s_waitcnt vmcnt(" vmstr ")" ::: "memory");                \
            __builtin_amdgcn_s_barrier();                                           \
            const int b = (t) & 3;                                                  \
            v4i af[4], bf[4];                                                       \
            _Pragma("unroll")                                                       \
            for (int kk = 0; kk < 4; ++kk) {                                        \
                const int ch = ((2 * kk + hi) ^ ar7) << 4;                          \
                const int chb = ((2 * kk + hi) ^ br7) << 4;                         \
                af[kk] = *(const v4i*)&lA[b][arow * 128 + ch];                      \
                bf[kk] = *(const v4i*)&lB[b][brow * 128 + chb];                     \
            }                                                                       \
            if (do_stage) STAGE((((t) + 3) & 3), ((t) + 3) * 128);                  \
            __builtin_amdgcn_s_setprio(1);                                          \
            _Pragma("unroll")                                                       \
            for (int kk = 0; kk < 4; ++kk)                                          \
                acc = __builtin_amdgcn_mfma_i32_32x32x32_i8(af[kk], bf[kk], acc, 0, 0, 0); \
            __builtin_amdgcn_s_setprio(0);                                          \
        }

    STAGE(0, 0);
    STAGE(1, 128);
    STAGE(2, 256);
    for (int t = 0; t < 13; ++t) TILE(t, "8", true);
    TILE(13, "8", false);
    TILE(14, "4", false);
    TILE(15, "0", false);
    #undef TILE
    #undef STAGE

    // ---- gate epilogue -> LDS (reuse lA[0]: no wave reads it after TILE 12,
    // and every wave is past barrier-15 before these writes) ----
    float* lds_g = (float*)&lA[0][0];        // [64 m-local][8 gcol-local]
    {
        const int ncol = n0 + wc * 32 + lo;
        const float bv = bias[ncol];
        const int gl = wc * 4 + (lo >> 3);   // gcol-local 0..7
        #pragma unroll
        for (int r = 0; r < 16; ++r) {
            const int mloc = wr * 32 + (r & 3) + 8 * (r >> 2) + 4 * hi;
            float z = ((float)acc[r] * DESCALE + bv) * GATE_SCALE;
            float gate = 1.0f / (1.0f + __expf(-z));
            gate += __shfl_xor(gate, 1);
            gate += __shfl_xor(gate, 2);
            gate += __shfl_xor(gate, 4);
            if (lo3 == 0)
                lds_g[mloc * 8 + gl] = gate * 0.125f;
        }
    }
    __syncthreads();

    // ---- apply: thread t -> h = t&1, j = (t>>1)&7, mb = t>>4 (0..15);
    // sites (m0 + mb + {0,16,32,48}, n = n0/8 + j), h-half rows. ----
    {
        const int h = tid & 1, j = (tid >> 1) & 7, mb = tid >> 4;
        const int n = (n0 >> 3) + j;

        float Ar_[4][8], Ai_[4][8];
        const float* An = Ac + n * 128;
        #pragma unroll
        for (int r = 0; r < 4; ++r) {
            const int o = h * 4 + r;
            #pragma unroll
            for (int p = 0; p < 2; ++p) {
                float4 f = *(const float4*)&An[o * 16 + h * 8 + p * 4];
                Ar_[r][p * 2]     = f.x;  Ai_[r][p * 2]     = f.y;
                Ar_[r][p * 2 + 1] = f.z;  Ai_[r][p * 2 + 1] = f.w;
            }
            #pragma unroll
            for (int p = 0; p < 2; ++p) {
                float4 f = *(const float4*)&An[o * 16 + (1 - h) * 8 + p * 4];
                Ar_[r][4 + p * 2]     = f.x;  Ai_[r][4 + p * 2]     = f.y;
                Ar_[r][4 + p * 2 + 1] = f.z;  Ai_[r][4 + p * 2 + 1] = f.w;
            }
        }

        #define CMV()                                                                   \
            {                                                                           \
                float pwr[4], pwi[4];                                                   \
                _Pragma("unroll")                                                       \
                for (int k2 = 0; k2 < 4; ++k2) {                                        \
                    pwr[k2] = __shfl_xor(wr2[k2], 1);                                   \
                    pwi[k2] = __shfl_xor(wi2[k2], 1);                                   \
                }                                                                       \
                _Pragma("unroll")                                                       \
                for (int r = 0; r < 4; ++r) {                                           \
                    float sr = 0.f, si = 0.f;                                           \
                    _Pragma("unroll")                                                   \
                    for (int jj = 0; jj < 4; ++jj) {                                    \
                        sr += Ar_[r][jj] * wr2[jj]     - Ai_[r][jj] * wi2[jj];          \
                        si += Ar_[r][jj] * wi2[jj]     + Ai_[r][jj] * wr2[jj];          \
                        sr += Ar_[r][4 + jj] * pwr[jj] - Ai_[r][4 + jj] * pwi[jj];      \
                        si += Ar_[r][4 + jj] * pwi[jj] + Ai_[r][4 + jj] * pwr[jj];      \
                    }                                                                   \
                    tr[r] = sr; ti[r] = si;                                             \
                }                                                                       \
            }

        #pragma unroll
        for (int mi = 0; mi < 4; ++mi) {
            const int mloc = mb + mi * 16;
            const int m = m0 + mloc;
            const int d = n * 8 + h * 4;
            const float4 fvr = *(const float4*)&xr[m * 1024 + d];
            const float4 fvi = *(const float4*)&xi[m * 1024 + d];
            float vr[4] = {fvr.x, fvr.y, fvr.z, fvr.w};
            float vi[4] = {fvi.x, fvi.y, fvi.z, fvi.w};
            const float gv = lds_g[mloc * 8 + j];
            const float c1 = -2.f * gv, c2 = -c1 * gv, c3 = -c2 * gv, c4 = -c3 * gv;
            float wr2[4], wi2[4], tr[4], ti[4];

            #pragma unroll
            for (int r = 0; r < 4; ++r) { wr2[r] = c4 * vr[r]; wi2[r] = c4 * vi[r]; }
            CMV();
            #pragma unroll
            for (int r = 0; r < 4; ++r) { wr2[r] = c3 * vr[r] + tr[r]; wi2[r] = c3 * vi[r] + ti[r]; }
            CMV();
            #pragma unroll
            for (int r = 0; r < 4; ++r) { wr2[r] = c2 * vr[r] + tr[r]; wi2[r] = c2 * vi[r] + ti[r]; }
            CMV();
            #pragma unroll
            for (int r = 0; r < 4; ++r) { wr2[r] = c1 * vr[r] + tr[r]; wi2[r] = c1 * vi[r] + ti[r]; }
            CMV();

            float4 s0 = {vr[0] + tr[0], vr[1] + tr[1], vr[2] + tr[2], vr[3] + tr[3]};
            float4 s1 = {vi[0] + ti[0], vi[1] + ti[1], vi[2] + ti[2], vi[3] + ti[3]};
            *(float4*)&outr[m * 1024 + d] = s0;
            *(float4*)&outi[m * 1024 + d] = s1;
        }
        #undef CMV
    }
}

// ---------------------------------------------------------------------------
extern "C" void kernel_launch(void* const* d_in, const int* in_sizes, int n_in,
                              void* d_out, int out_size, void* d_ws, size_t ws_size,
                              hipStream_t stream) {
    const float* xr = (const float*)d_in[0];
    const float* xi = (const float*)d_in[1];
    const float* Ar = (const float*)d_in[2];
    const float* Ai = (const float*)d_in[3];
    const float* W  = (const float*)d_in[4];
    const float* bg = (const float*)d_in[5];
    float* out = (float*)d_out;

    char* ws = (char*)d_ws;
    signed char* xq = (signed char*)(ws);            // 4194304 B
    signed char* wq = (signed char*)(ws + 4194304);  // 2097152 B
    float*  Ac = (float*)(ws + 6291456);             // 65536 B

    hipLaunchKernelGGL(convert_kernel, dim3(1056), dim3(256), 0, stream,
                       xr, xi, W, Ar, Ai, xq, wq, Ac);
    hipLaunchKernelGGL(gemm_apply_kernel, dim3(512), dim3(256), 0, stream,
                       xq, wq, bg, xr, xi, Ac, out, out + 2 * 1024 * 1024);
}